// Round 6
// baseline (119.311 us; speedup 1.0000x reference)
//
#include <hip/hip_runtime.h>

// ChamferLoss: B=4, N=M=8192, D=3, fp32. Scalar out.
// MFMA formulation: one v_mfma_f32_32x32x16_f16 emits a full 32x32 tile of
//   d[n,m] = xn + yn - 2 x.y
// via split-f16 K-packing (13 of 16 slots):
//   k0-2: xh*yh'  k3-5: xl*yh'  k6-8: xh*yl'   (y' = -2y, split AFTER scaling)
//   k9: xnh*1  k10: xnl*1  k11: 1*ynh  k12: 1*ynl  k13-15: 0
// Error ~3e-6 << 9.3e-4 threshold. Both directions served by the same tile:
// rowmin elementwise in regs, colmin per-tile tree + LDS atomicMin (keyed).
// Layouts: C/D 32x32 col=lane&31,row=(reg&3)+8*(reg>>2)+4*(lane>>5) [m74/m101];
// A/B: k=(lane>>5)*8+j (gfx950 contiguous-8 pattern, m120-verified for 16x16).

#define BATCH   4
#define NPTS    8192
#define TPB     256
#define MSLICE  1024                 // m columns per block
#define NBAND   256                  // n rows per block
#define NTPW    2                    // n-tiles (32 rows) per wave
#define MT      (MSLICE / 32)        // 32 m-tiles per block
#define NBANDS  (NPTS / NBAND)       // 32
#define NSLICES (NPTS / MSLICE)      // 8

typedef _Float16 h8  __attribute__((ext_vector_type(8)));
typedef float    f16v __attribute__((ext_vector_type(16)));

__device__ __forceinline__ unsigned keyf(float f) {
    unsigned u = __float_as_uint(f);
    return u ^ ((unsigned)((int)u >> 31) | 0x80000000u);   // order-preserving incl. negatives
}
__device__ __forceinline__ float unkeyf(unsigned k) {
    return __uint_as_float(k ^ (((int)k < 0) ? 0x80000000u : 0xFFFFFFFFu));
}
__device__ __forceinline__ void split16(float v, _Float16& hi, _Float16& lo) {
    hi = (_Float16)v;
    lo = (_Float16)(v - (float)hi);
}

__global__ __launch_bounds__(TPB, 4) void chamfer_mfma(const float* __restrict__ xg,
                                                       const float* __restrict__ yg,
                                                       float* __restrict__ rowp,
                                                       float* __restrict__ colp) {
    __shared__ h8 bfrag[MSLICE * 2];          // per m point: half0,half1 B-fragments (32 KB)
    __shared__ unsigned cmk[MSLICE];          // keyed colmin accum (4 KB)
    __shared__ unsigned rmk[NBAND];           // keyed rowmin accum (1 KB)

    const int tid   = threadIdx.x;
    const int slice = blockIdx.x;             // m-slice [0,8)
    const int band  = blockIdx.y;             // n-band  [0,32)
    const int b     = blockIdx.z;
    const int lane  = tid & 63, wave = tid >> 6;
    const int col   = lane & 31, hv = lane >> 5;

    // ---- stage B fragments (y side), 4 points per thread ----
    const float* ybase = yg + ((size_t)b * NPTS + slice * MSLICE) * 3;
#pragma unroll
    for (int i = 0; i < MSLICE / TPB; ++i) {
        const int p = tid + i * TPB;
        float y0 = ybase[p * 3 + 0], y1 = ybase[p * 3 + 1], y2 = ybase[p * 3 + 2];
        _Float16 h0, l0, h1, l1, h2, l2, ynh, ynl;
        split16(-2.0f * y0, h0, l0);
        split16(-2.0f * y1, h1, l1);
        split16(-2.0f * y2, h2, l2);
        split16(fmaf(y0, y0, fmaf(y1, y1, y2 * y2)), ynh, ynl);
        h8 f0 = {h0, h1, h2, h0, h1, h2, l0, l1};                       // k0..7
        h8 f1 = {l2, (_Float16)1.0f, (_Float16)1.0f, ynh, ynl,
                 (_Float16)0.0f, (_Float16)0.0f, (_Float16)0.0f};       // k8..15
        bfrag[p * 2 + 0] = f0;
        bfrag[p * 2 + 1] = f1;
        cmk[p] = 0xFFFFFFFFu;
    }
    if (tid < NBAND) rmk[tid] = 0xFFFFFFFFu;

    // ---- A fragments for this wave's 2 n-tiles (x side) ----
    h8 af[NTPW];
#pragma unroll
    for (int t = 0; t < NTPW; ++t) {
        const int n = band * NBAND + (wave * NTPW + t) * 32 + col;
        const float* xp = xg + ((size_t)b * NPTS + n) * 3;
        float x0 = xp[0], x1 = xp[1], x2 = xp[2];
        _Float16 h0, l0, h1, l1, h2, l2, xnh, xnl;
        split16(x0, h0, l0);
        split16(x1, h1, l1);
        split16(x2, h2, l2);
        split16(fmaf(x0, x0, fmaf(x1, x1, x2 * x2)), xnh, xnl);
        h8 a0 = {h0, h1, h2, l0, l1, l2, h0, h1};                       // k0..7
        h8 a1 = {h2, xnh, xnl, (_Float16)1.0f, (_Float16)1.0f,
                 (_Float16)0.0f, (_Float16)0.0f, (_Float16)0.0f};       // k8..15
        af[t] = hv ? a1 : a0;
    }
    __syncthreads();

    f16v zf = {};                              // zero accumulator (loop-invariant)
    f16v rm0, rm1;
#pragma unroll
    for (int i = 0; i < 16; ++i) { rm0[i] = 3.0e38f; rm1[i] = 3.0e38f; }

    for (int mt = 0; mt < MT; ++mt) {
        const h8 bf = bfrag[(mt * 32 + col) * 2 + hv];   // ds_read_b128, conflict-free
        f16v d0 = __builtin_amdgcn_mfma_f32_32x32x16_f16(af[0], bf, zf, 0, 0, 0);
        f16v d1 = __builtin_amdgcn_mfma_f32_32x32x16_f16(af[1], bf, zf, 0, 0, 0);

        float tt[16];
#pragma unroll
        for (int i = 0; i < 16; ++i) {
            rm0[i] = fminf(rm0[i], d0[i]);
            rm1[i] = fminf(rm1[i], d1[i]);
            tt[i]  = fminf(d0[i], d1[i]);
        }
#pragma unroll
        for (int s = 8; s > 0; s >>= 1)
#pragma unroll
            for (int i = 0; i < 8; ++i)
                if (i < s) tt[i] = fminf(tt[i], tt[i + s]);
        atomicMin(&cmk[mt * 32 + col], keyf(tt[0]));     // ds atomic, both halves merge
    }

    // rowmin epilogue: 32 keyed ds-atomics per wave (once per block)
#pragma unroll
    for (int i = 0; i < 16; ++i) {
        const int row = (i & 3) + 8 * (i >> 2) + 4 * hv;
        atomicMin(&rmk[(wave * NTPW + 0) * 32 + row], keyf(rm0[i]));
        atomicMin(&rmk[(wave * NTPW + 1) * 32 + row], keyf(rm1[i]));
    }
    __syncthreads();

    // ---- merge to global partials (plain floats, coalesced) ----
    float* rp = rowp + (((size_t)b * NBANDS + band) * NSLICES + slice) * NBAND;
    rp[tid] = unkeyf(rmk[tid]);                // NBAND == TPB
    float* cp = colp + (((size_t)b * NSLICES + slice) * NBANDS + band) * MSLICE;
#pragma unroll
    for (int i = 0; i < MSLICE / TPB; ++i)
        cp[tid + i * TPB] = unkeyf(cmk[tid + i * TPB]);
}

__global__ __launch_bounds__(TPB) void chamfer_reduce(const float* __restrict__ rowp,
                                                      const float* __restrict__ colp,
                                                      float* __restrict__ out) {
    const int tid = threadIdx.x;
    const int g = blockIdx.x * TPB + tid;      // [0, 2*BATCH*NPTS)
    float v = 3.0e38f;
    if (g < BATCH * NPTS) {
        const int b = g / NPTS, nn = g - b * NPTS;
        const int band = nn / NBAND, nl = nn & (NBAND - 1);
        const float* p = rowp + ((size_t)(b * NBANDS + band) * NSLICES) * NBAND + nl;
#pragma unroll
        for (int s = 0; s < NSLICES; ++s) v = fminf(v, p[s * NBAND]);
    } else {
        const int g2 = g - BATCH * NPTS;
        const int b = g2 / NPTS, mm = g2 - b * NPTS;
        const int sl = mm / MSLICE, ml = mm & (MSLICE - 1);
        const float* p = colp + ((size_t)(b * NSLICES + sl) * NBANDS) * MSLICE + ml;
#pragma unroll
        for (int s = 0; s < NBANDS; ++s) v = fminf(v, p[s * MSLICE]);
    }
    // block sum -> single atomic
    float w = v;
#pragma unroll
    for (int off = 32; off > 0; off >>= 1)
        w += __shfl_down(w, off, 64);
    __shared__ float ss[TPB / 64];
    if ((tid & 63) == 0) ss[tid >> 6] = w;
    __syncthreads();
    if (tid == 0)
        atomicAdd(out, (ss[0] + ss[1] + ss[2] + ss[3]) * (1.0f / (float)(BATCH * NPTS)));
}

extern "C" void kernel_launch(void* const* d_in, const int* in_sizes, int n_in,
                              void* d_out, int out_size, void* d_ws, size_t ws_size,
                              hipStream_t stream) {
    const float* x = (const float*)d_in[0];
    const float* y = (const float*)d_in[1];
    float* out = (float*)d_out;
    float* rowp = (float*)d_ws;                               // 4*32*8*256  = 1 MB
    float* colp = rowp + (size_t)BATCH * NBANDS * NSLICES * NBAND;  // 4*8*32*1024 = 4 MB

    hipMemsetAsync(out, 0, sizeof(float), stream);
    chamfer_mfma<<<dim3(NSLICES, NBANDS, BATCH), TPB, 0, stream>>>(x, y, rowp, colp);
    chamfer_reduce<<<dim3(2 * BATCH * NPTS / TPB), TPB, 0, stream>>>(rowp, colp, out);
}